// Round 12
// baseline (1744.740 us; speedup 1.0000x reference)
//
#include <hip/hip_runtime.h>
#include <math.h>

// ODE-RNN encoder, fully fused: one 64-lane wave per batch sample.
// r10 post-mortem: weights-in-LDS helped (1601->1483us) but ~1600 cy/eval of
// stall remains: LDSFENCE is a full compiler barrier, so each layer's 16
// static-address weight ds_read_b128 are trapped BEHIND the act write->fence
// and their latency+drain is exposed per layer. This round: software-prefetch
// each layer's weights into register arrays BEFORE the preceding fence
// (w1r issues under L0's readlane VALU; w2r issues under L1's FMAs), so
// weight-read latency overlaps compute. amdgpu_waves_per_eu(1,1) lifts the
// 128-VGPR RA budget for the ~150-VGPR peak (2 waves/CU by construction, so
// occupancy is unaffected; r8 proved the attribute is perf-neutral).
// FMA pairing/summation order BIT-IDENTICAL to r10 (absmax 0.0).
//  - W1/W2 in LDS, stride-68 rows (r10: 0 bank conflicts).
//  - FSAL, readlane L0/GRU, barrier-free single-wave hot loop kept.

namespace {
constexpr int LSEQ = 256;
constexpr int WSTR = 68;   // LDS weight row stride in dwords (64 + 4 pad)

typedef float f32x2 __attribute__((ext_vector_type(2)));

__device__ __forceinline__ f32x2 mk2(float a, float b) {
    f32x2 r; r.x = a; r.y = b; return r;
}
__device__ __forceinline__ f32x2 fma2(f32x2 a, f32x2 b, f32x2 c) {
    return __builtin_elementwise_fma(a, b, c);
}
__device__ __forceinline__ float RL(float v, int k) {   // broadcast lane k
    return __uint_as_float(__builtin_amdgcn_readlane(__float_as_uint(v), k));
}
#define LDSFENCE() asm volatile("" ::: "memory")

__device__ __forceinline__ float tanh_f(float x) {
    float e = exp2f(x * 2.8853900817779268f);
    return 1.0f - 2.0f * __builtin_amdgcn_rcpf(e + 1.0f);
}
__device__ __forceinline__ float sigm_f(float x) {
    return __builtin_amdgcn_rcpf(1.0f + exp2f(x * -1.4426950408889634f));
}
} // namespace

extern "C" __global__ void __launch_bounds__(64)
__attribute__((amdgpu_waves_per_eu(1, 1)))
odern_kernel(const float* __restrict__ x_seq,
             const float* __restrict__ W0, const float* __restrict__ b0,
             const float* __restrict__ W1, const float* __restrict__ b1,
             const float* __restrict__ W2, const float* __restrict__ b2,
             const float* __restrict__ W3, const float* __restrict__ b3,
             const float* __restrict__ Wih, const float* __restrict__ Whh,
             const float* __restrict__ bih, const float* __restrict__ bn,
             const float* __restrict__ Wp, const float* __restrict__ bp,
             float* __restrict__ out)
{
    const int j   = threadIdx.x;      // 0..63
    const int b   = blockIdx.x;       // sample
    const int i16 = j & 15;           // owned y-component (replicated x4)

    __shared__ __align__(16) float s_w1[64 * WSTR];  // W1 rows, stride 68
    __shared__ __align__(16) float s_w2[64 * WSTR];  // W2 rows, stride 68
    __shared__ __align__(16) float s_hA[64];
    __shared__ __align__(16) float s_hB[64];
    __shared__ __align__(16) float s_x[2 * LSEQ];
    __shared__ float s_ig[48];
    __shared__ float s_hg[48];

    // ---------------- x row -> LDS (once) ----------------
    {
        const float4* xv = (const float4*)(x_seq + (long)b * (2 * LSEQ));
        float4 t0 = xv[j];
        float4 t1 = xv[j + 64];
        ((float4*)s_x)[j]      = t0;
        ((float4*)s_x)[j + 64] = t1;
    }
    // ---------------- W1/W2 -> LDS (once), stride-68 rows --------------
    {
        const float4* g1 = (const float4*)(W1 + j * 64);
        const float4* g2 = (const float4*)(W2 + j * 64);
        float* r1 = s_w1 + j * WSTR;
        float* r2 = s_w2 + j * WSTR;
        #pragma unroll
        for (int q = 0; q < 16; ++q) {
            *(float4*)(r1 + 4 * q) = g1[q];
            *(float4*)(r2 + 4 * q) = g2[q];
        }
    }

    // ---------------- small weights (L1-resident remat is fine) --------
    float w0s[16], whs[16];
    f32x2 w3v[8];
    {
        const float4* p = (const float4*)(W0 + j * 16);
        #pragma unroll
        for (int q = 0; q < 4; ++q) { float4 u = p[q];
            w0s[4*q]=u.x; w0s[4*q+1]=u.y; w0s[4*q+2]=u.z; w0s[4*q+3]=u.w; }
    }
    {
        const float4* p = (const float4*)(W3 + i16 * 64 + (j >> 4) * 16);
        #pragma unroll
        for (int q = 0; q < 4; ++q) { float4 u = p[q];
            w3v[2*q] = mk2(u.x, u.y); w3v[2*q+1] = mk2(u.z, u.w); }
    }
    const int jg = (j < 48) ? j : 47;   // clamp for 48-row GRU mats
    {
        const float4* p = (const float4*)(Whh + jg * 16);
        #pragma unroll
        for (int q = 0; q < 4; ++q) { float4 u = p[q];
            whs[4*q]=u.x; whs[4*q+1]=u.y; whs[4*q+2]=u.z; whs[4*q+3]=u.w; }
    }
    const float wih0 = Wih[jg * 2], wih1 = Wih[jg * 2 + 1], bihj = bih[jg];
    const float bs0 = b0[j], bs1 = b1[j], bs2 = b2[j];
    const float b3r = b3[i16], bnr = bn[i16], wpr = Wp[i16];

    __syncthreads();   // one-time: staging visible; hot loop is barrier-free

    const float* w1row = s_w1 + j * WSTR;
    const float* w2row = s_w2 + j * WSTR;

    // 64-wide dot from PRE-LOADED weight regs; acts uniform broadcast.
    // Pairing/summation order == r10 (bit-exact): even q -> a0(xy),a1(zw);
    // odd q -> a2(xy),a3(zw); result ((a0+a1)+(a2+a3)).x+.y
    auto dot64pre = [&](const float4* wr, const float4* act, float bias) -> float {
        f32x2 a0 = mk2(bias, 0.f), a1 = mk2(0.f, 0.f),
              a2 = mk2(0.f, 0.f),  a3 = mk2(0.f, 0.f);
        #pragma unroll
        for (int q = 0; q < 16; q += 2) {
            float4 w4 = wr[q];
            float4 u  = act[q];
            a0 = fma2(mk2(w4.x, w4.y), mk2(u.x, u.y), a0);
            a1 = fma2(mk2(w4.z, w4.w), mk2(u.z, u.w), a1);
            float4 w5 = wr[q + 1];
            float4 v  = act[q + 1];
            a2 = fma2(mk2(w5.x, w5.y), mk2(v.x, v.y), a2);
            a3 = fma2(mk2(w5.z, w5.w), mk2(v.z, v.w), a3);
        }
        f32x2 s = (a0 + a1) + (a2 + a3);
        return s.x + s.y;
    };
    // L3 16-wide packed dot (split-k chunk), order == r10.
    auto dot16pk = [&](const float4* p4, const f32x2* wv) -> float {
        f32x2 a0 = mk2(0.f, 0.f), a1 = mk2(0.f, 0.f);
        float4 u = p4[0];
        a0 = fma2(wv[0], mk2(u.x, u.y), a0);
        a1 = fma2(wv[1], mk2(u.z, u.w), a1);
        float4 v = p4[1];
        a0 = fma2(wv[2], mk2(v.x, v.y), a0);
        a1 = fma2(wv[3], mk2(v.z, v.w), a1);
        float4 w = p4[2];
        a0 = fma2(wv[4], mk2(w.x, w.y), a0);
        a1 = fma2(wv[5], mk2(w.z, w.w), a1);
        float4 z = p4[3];
        a0 = fma2(wv[6], mk2(z.x, z.y), a0);
        a1 = fma2(wv[7], mk2(z.z, z.w), a1);
        f32x2 s = a0 + a1;
        return s.x + s.y;
    };

    // MLP eval; ys is lane-replicated (lane k<16 holds component k).
    auto mlp = [&](float ys) -> float {
        // --- prefetch L1 weight row: issues BEFORE fence, latency hidden
        //     under L0's readlane/VALU work.
        float4 w1r[16];
        #pragma unroll
        for (int q = 0; q < 16; ++q) w1r[q] = ((const float4*)w1row)[q];
        // L0: 16 -> 64 via readlane broadcasts (no LDS round-trip).
        float t0 = bs0, t1 = 0.f, t2 = 0.f, t3 = 0.f;
        #pragma unroll
        for (int k = 0; k < 16; k += 4) {
            t0 = fmaf(w0s[k + 0], RL(ys, k + 0), t0);
            t1 = fmaf(w0s[k + 1], RL(ys, k + 1), t1);
            t2 = fmaf(w0s[k + 2], RL(ys, k + 2), t2);
            t3 = fmaf(w0s[k + 3], RL(ys, k + 3), t3);
        }
        float a = tanh_f((t0 + t2) + (t1 + t3));
        s_hA[j] = a;
        LDSFENCE();                 // same-wave DS in-order; stop IR reorder
        // --- prefetch L2 weight row: issues alongside L1's act reads/FMAs,
        //     consumed after the next fence.
        float4 w2r[16];
        #pragma unroll
        for (int q = 0; q < 16; ++q) w2r[q] = ((const float4*)w2row)[q];
        float a1 = tanh_f(dot64pre(w1r, (const float4*)s_hA, bs1));
        s_hB[j] = a1;
        LDSFENCE();
        float a2 = tanh_f(dot64pre(w2r, (const float4*)s_hB, bs2));
        s_hA[j] = a2;
        LDSFENCE();
        float p = dot16pk((const float4*)s_hA + (j >> 4) * 4, w3v);
        p += __shfl_xor(p, 16);
        p += __shfl_xor(p, 32);
        LDSFENCE();
        return p + b3r;
    };

    // Tsit5 tableau (f32)
    const float A21 = 0.161f;
    const float A31 = -0.008480655492356989f, A32 = 0.335480655492357f;
    const float A41 = 2.8971530571054935f, A42 = -6.359448489975075f, A43 = 4.3622954328695815f;
    const float A51 = 5.325864828439257f, A52 = -11.748883564062828f, A53 = 7.4955393428898365f, A54 = -0.09249506636175525f;
    const float A61 = 5.86145544294642f, A62 = -12.92096931784711f, A63 = 8.159367898576159f, A64 = -0.071584973281401f, A65 = -0.028269050394068383f;
    const float B1 = 0.09646076681806523f, B2 = 0.01f, B3 = 0.4798896504144996f,
                B4 = 1.379008574103742f, B5 = -3.290069515436081f, B6 = 2.324710524099774f;
    const float E1 = -0.00178001105222577714f, E2 = -0.0008164344596567469f,
                E3 = 0.007880878010261995f, E4 = -0.1447110071732629f,
                E5 = 0.5823571654525552f, E6 = -0.45808210592918697f, E7 = 0.015151515151515152f;
    const float TDONE = (float)(1.0 - 1e-7);

    float y = 0.0f;                       // h0 = zeros (replicated component i16)

    #pragma unroll 1
    for (int l = 0; l < LSEQ; ++l) {
        // ---------------- adaptive Tsit5 on [0,1], dt0 = 1, FSAL ----------
        float t = 0.f, dt = 1.f;
        float k1 = mlp(y);                // first eval of this solve
        #pragma unroll 1
        for (int it = 0; it < 12; ++it) {
            if (t >= TDONE) break;        // identical to reference's frozen iters
            float dtc = fminf(dt, 1.0f - t);
            float k2 = mlp(fmaf(dtc, A21 * k1, y));
            float k3 = mlp(fmaf(dtc, A31*k1 + A32*k2, y));
            float k4 = mlp(fmaf(dtc, A41*k1 + A42*k2 + A43*k3, y));
            float k5 = mlp(fmaf(dtc, A51*k1 + A52*k2 + A53*k3 + A54*k4, y));
            float k6 = mlp(fmaf(dtc, A61*k1 + A62*k2 + A63*k3 + A64*k4 + A65*k5, y));
            float ynew = fmaf(dtc, B1*k1 + B2*k2 + B3*k3 + B4*k4 + B5*k5 + B6*k6, y);
            float k7 = mlp(ynew);
            float yerr = dtc * (E1*k1 + E2*k2 + E3*k3 + E4*k4 + E5*k5 + E6*k6 + E7*k7);
            float sc = fmaf(0.01f, fmaxf(fabsf(y), fabsf(ynew)), 1e-4f);
            float e = yerr / sc;          // keep IEEE: feeds the accept branch
            float e2 = e * e;
            e2 += __shfl_xor(e2, 1); e2 += __shfl_xor(e2, 2);
            e2 += __shfl_xor(e2, 4); e2 += __shfl_xor(e2, 8);
            float err = sqrtf(e2 * 0.0625f);
            if (err <= 1.0f) { y = ynew; t += dtc; k1 = k7; }  // FSAL
            float fac = 0.9f * exp2f(-0.2f * log2f(fmaxf(err, 1e-10f)));
            fac = fminf(fmaxf(fac, 0.2f), 10.0f);
            dt = dtc * fac;
        }
        // ---------------- GRU observation update ----------------
        float x0 = s_x[2*l], x1 = s_x[2*l + 1];
        // hg = Whh[jg,:] . y via readlane (same summation order as before)
        float h0 = 0.f, h1 = 0.f, h2 = 0.f, h3 = 0.f;
        #pragma unroll
        for (int k = 0; k < 16; k += 4) {
            h0 = fmaf(whs[k + 0], RL(y, k + 0), h0);
            h1 = fmaf(whs[k + 1], RL(y, k + 1), h1);
            h2 = fmaf(whs[k + 2], RL(y, k + 2), h2);
            h3 = fmaf(whs[k + 3], RL(y, k + 3), h3);
        }
        float hg = (h0 + h2) + (h1 + h3);
        float ig = fmaf(wih0, x0, fmaf(wih1, x1, bihj));
        if (j < 48) { s_ig[j] = ig; s_hg[j] = hg; }
        LDSFENCE();
        float ir = s_ig[i16], iz = s_ig[16+i16], in_ = s_ig[32+i16];
        float hr = s_hg[i16], hz = s_hg[16+i16], hn = s_hg[32+i16];
        float r = sigm_f(ir + hr);
        float z = sigm_f(iz + hz);
        float n = tanh_f(fmaf(r, hn + bnr, in_));
        y = n + z * (y - n);
        LDSFENCE();
    }

    // ---------------- projection: out[b] = Wp . h + bp ----------------
    float pv = y * wpr;
    pv += __shfl_xor(pv, 1); pv += __shfl_xor(pv, 2);
    pv += __shfl_xor(pv, 4); pv += __shfl_xor(pv, 8);
    if (j == 0) out[b] = pv + bp[0];
}

extern "C" void kernel_launch(void* const* d_in, const int* in_sizes, int n_in,
                              void* d_out, int out_size, void* d_ws, size_t ws_size,
                              hipStream_t stream)
{
    odern_kernel<<<dim3(512), dim3(64), 0, stream>>>(
        (const float*)d_in[0],
        (const float*)d_in[1],  (const float*)d_in[2],
        (const float*)d_in[3],  (const float*)d_in[4],
        (const float*)d_in[5],  (const float*)d_in[6],
        (const float*)d_in[7],  (const float*)d_in[8],
        (const float*)d_in[9],  (const float*)d_in[10],
        (const float*)d_in[11], (const float*)d_in[12],
        (const float*)d_in[13], (const float*)d_in[14],
        (float*)d_out);
}

// Round 13
// 1629.065 us; speedup vs baseline: 1.0710x; 1.0710x over previous
//
#include <hip/hip_runtime.h>
#include <math.h>

// ODE-RNN encoder, fully fused: one 64-lane wave per batch sample.
// r12 post-mortem: lgkmcnt is ONE in-order queue -> prefetching the next
// layer's LDS weight reads ahead of this layer's act reads forces the act
// consumers to drain the prefetch (1744us, regression). r10 (1483us) stalls
// ~1600cy/eval on: 3x act LDS round-trips + fences + in-order read drains +
// 2-waves/CU DS-pipe contention (32 weight b128/eval).
// THIS ROUND: activations NEVER touch LDS. Acts live one-per-lane in regs;
// dot loops are fully unrolled so lane indices are compile-time constants ->
// v_readlane broadcasts (VALU) replace all act LDS traffic, all fences, all
// DS ordering hazards. Weights return to global/L1 (vmcnt pipe, r9-proven,
// now uncontended; W1+W2=32KB L1-resident, shared by both waves/CU).
// L3 restructured: per-lane full 64-dot as 4 canonical 16-chunks combined
// ((c0+c1)+(c2+c3)) — BIT-IDENTICAL to the old shfl_xor16/32 tree.
// L1/L2: 8 scalar chains replicating r10's packed element assignment and
// final (c0+c2)+(c4+c6) / (c1+c3)+(c5+c7) / sx+sy order exactly.
// MLP is now fence-free, barrier-free, LDS-free. Only s_x + GRU gate swap
// use LDS (2 fences per STEP, not per eval).

namespace {
constexpr int LSEQ = 256;

__device__ __forceinline__ float RL(float v, int k) {   // broadcast lane k
    return __uint_as_float(__builtin_amdgcn_readlane(__float_as_uint(v), k));
}
#define LDSFENCE() asm volatile("" ::: "memory")

__device__ __forceinline__ float tanh_f(float x) {
    float e = exp2f(x * 2.8853900817779268f);
    return 1.0f - 2.0f * __builtin_amdgcn_rcpf(e + 1.0f);
}
__device__ __forceinline__ float sigm_f(float x) {
    return __builtin_amdgcn_rcpf(1.0f + exp2f(x * -1.4426950408889634f));
}
} // namespace

extern "C" __global__ void __launch_bounds__(64, 1)
odern_kernel(const float* __restrict__ x_seq,
             const float* __restrict__ W0, const float* __restrict__ b0,
             const float* __restrict__ W1, const float* __restrict__ b1,
             const float* __restrict__ W2, const float* __restrict__ b2,
             const float* __restrict__ W3, const float* __restrict__ b3,
             const float* __restrict__ Wih, const float* __restrict__ Whh,
             const float* __restrict__ bih, const float* __restrict__ bn,
             const float* __restrict__ Wp, const float* __restrict__ bp,
             float* __restrict__ out)
{
    const int j   = threadIdx.x;      // 0..63
    const int b   = blockIdx.x;       // sample
    const int i16 = j & 15;           // owned y-component (replicated x4)

    __shared__ __align__(16) float s_x[2 * LSEQ];
    __shared__ float s_ig[48];
    __shared__ float s_hg[48];

    // ---------------- x row -> LDS (once) ----------------
    {
        const float4* xv = (const float4*)(x_seq + (long)b * (2 * LSEQ));
        float4 t0 = xv[j];
        float4 t1 = xv[j + 64];
        ((float4*)s_x)[j]      = t0;
        ((float4*)s_x)[j + 64] = t1;
    }

    // ---------------- small weights (L1-resident remat is fine) --------
    float w0s[16], whs[16];
    {
        const float4* p = (const float4*)(W0 + j * 16);
        #pragma unroll
        for (int q = 0; q < 4; ++q) { float4 u = p[q];
            w0s[4*q]=u.x; w0s[4*q+1]=u.y; w0s[4*q+2]=u.z; w0s[4*q+3]=u.w; }
    }
    const int jg = (j < 48) ? j : 47;   // clamp for 48-row GRU mats
    {
        const float4* p = (const float4*)(Whh + jg * 16);
        #pragma unroll
        for (int q = 0; q < 4; ++q) { float4 u = p[q];
            whs[4*q]=u.x; whs[4*q+1]=u.y; whs[4*q+2]=u.z; whs[4*q+3]=u.w; }
    }
    const float wih0 = Wih[jg * 2], wih1 = Wih[jg * 2 + 1], bihj = bih[jg];
    const float bs0 = b0[j], bs1 = b1[j], bs2 = b2[j];
    const float b3r = b3[i16], bnr = bn[i16], wpr = Wp[i16];

    // Per-lane weight row pointers (global; L1-resident, remat'd each eval)
    const float4* w1p = (const float4*)(W1 + j * 64);
    const float4* w2p = (const float4*)(W2 + j * 64);
    const float4* w3p = (const float4*)(W3 + i16 * 64);   // full row of out i16

    __syncthreads();   // one-time: s_x visible; hot loop is barrier-free

    // 64-wide dot: weights global, acts via readlane (av per-lane).
    // 8 scalar chains == r10's packed a0..a3 {.x,.y} element map; final
    // (c0+c2)+(c4+c6), (c1+c3)+(c5+c7), sx+sy — BIT-IDENTICAL order.
    auto dot64rl = [&](const float4* wp, float av, float bias) -> float {
        float c0 = bias, c1 = 0.f, c2 = 0.f, c3 = 0.f,
              c4 = 0.f,  c5 = 0.f, c6 = 0.f, c7 = 0.f;
        #pragma unroll
        for (int q = 0; q < 16; q += 2) {
            float4 w4 = wp[q];
            c0 = fmaf(w4.x, RL(av, 4*q + 0), c0);
            c1 = fmaf(w4.y, RL(av, 4*q + 1), c1);
            c2 = fmaf(w4.z, RL(av, 4*q + 2), c2);
            c3 = fmaf(w4.w, RL(av, 4*q + 3), c3);
            float4 w5 = wp[q + 1];
            c4 = fmaf(w5.x, RL(av, 4*q + 4), c4);
            c5 = fmaf(w5.y, RL(av, 4*q + 5), c5);
            c6 = fmaf(w5.z, RL(av, 4*q + 6), c6);
            c7 = fmaf(w5.w, RL(av, 4*q + 7), c7);
        }
        float sx = (c0 + c2) + (c4 + c6);
        float sy = (c1 + c3) + (c5 + c7);
        return sx + sy;
    };
    // 16-chunk of L3: elements e0..e0+15, canonical (v0+v2)+(v1+v3) order.
    auto dot16rl = [&](const float4* wp, float av, int e0) -> float {
        float v0 = 0.f, v1 = 0.f, v2 = 0.f, v3 = 0.f;
        #pragma unroll
        for (int q = 0; q < 4; ++q) {
            float4 w4 = wp[q];
            v0 = fmaf(w4.x, RL(av, e0 + 4*q + 0), v0);
            v1 = fmaf(w4.y, RL(av, e0 + 4*q + 1), v1);
            v2 = fmaf(w4.z, RL(av, e0 + 4*q + 2), v2);
            v3 = fmaf(w4.w, RL(av, e0 + 4*q + 3), v3);
        }
        return (v0 + v2) + (v1 + v3);
    };

    // MLP eval; ys is lane-replicated (lane k<16 holds component k).
    // Fence-free, LDS-free: acts stay in registers, broadcast by readlane.
    auto mlp = [&](float ys) -> float {
        // L0: 16 -> 64 (canonical t-chain order)
        float t0 = bs0, t1 = 0.f, t2 = 0.f, t3 = 0.f;
        #pragma unroll
        for (int k = 0; k < 16; k += 4) {
            t0 = fmaf(w0s[k + 0], RL(ys, k + 0), t0);
            t1 = fmaf(w0s[k + 1], RL(ys, k + 1), t1);
            t2 = fmaf(w0s[k + 2], RL(ys, k + 2), t2);
            t3 = fmaf(w0s[k + 3], RL(ys, k + 3), t3);
        }
        float a  = tanh_f((t0 + t2) + (t1 + t3));
        float a1 = tanh_f(dot64rl(w1p, a,  bs1));   // L1: 64 -> 64
        float a2 = tanh_f(dot64rl(w2p, a1, bs2));   // L2: 64 -> 64
        // L3: 64 -> 16, per-lane full dot as 4 chunks; ((c0+c1)+(c2+c3))
        // == the old shfl_xor16/32 tree, bit-identical.
        float ch0 = dot16rl(w3p + 0,  a2, 0);
        float ch1 = dot16rl(w3p + 4,  a2, 16);
        float ch2 = dot16rl(w3p + 8,  a2, 32);
        float ch3 = dot16rl(w3p + 12, a2, 48);
        return ((ch0 + ch1) + (ch2 + ch3)) + b3r;
    };

    // Tsit5 tableau (f32)
    const float A21 = 0.161f;
    const float A31 = -0.008480655492356989f, A32 = 0.335480655492357f;
    const float A41 = 2.8971530571054935f, A42 = -6.359448489975075f, A43 = 4.3622954328695815f;
    const float A51 = 5.325864828439257f, A52 = -11.748883564062828f, A53 = 7.4955393428898365f, A54 = -0.09249506636175525f;
    const float A61 = 5.86145544294642f, A62 = -12.92096931784711f, A63 = 8.159367898576159f, A64 = -0.071584973281401f, A65 = -0.028269050394068383f;
    const float B1 = 0.09646076681806523f, B2 = 0.01f, B3 = 0.4798896504144996f,
                B4 = 1.379008574103742f, B5 = -3.290069515436081f, B6 = 2.324710524099774f;
    const float E1 = -0.00178001105222577714f, E2 = -0.0008164344596567469f,
                E3 = 0.007880878010261995f, E4 = -0.1447110071732629f,
                E5 = 0.5823571654525552f, E6 = -0.45808210592918697f, E7 = 0.015151515151515152f;
    const float TDONE = (float)(1.0 - 1e-7);

    float y = 0.0f;                       // h0 = zeros (replicated component i16)

    #pragma unroll 1
    for (int l = 0; l < LSEQ; ++l) {
        // ---------------- adaptive Tsit5 on [0,1], dt0 = 1, FSAL ----------
        float t = 0.f, dt = 1.f;
        float k1 = mlp(y);                // first eval of this solve
        #pragma unroll 1
        for (int it = 0; it < 12; ++it) {
            if (t >= TDONE) break;        // identical to reference's frozen iters
            float dtc = fminf(dt, 1.0f - t);
            float k2 = mlp(fmaf(dtc, A21 * k1, y));
            float k3 = mlp(fmaf(dtc, A31*k1 + A32*k2, y));
            float k4 = mlp(fmaf(dtc, A41*k1 + A42*k2 + A43*k3, y));
            float k5 = mlp(fmaf(dtc, A51*k1 + A52*k2 + A53*k3 + A54*k4, y));
            float k6 = mlp(fmaf(dtc, A61*k1 + A62*k2 + A63*k3 + A64*k4 + A65*k5, y));
            float ynew = fmaf(dtc, B1*k1 + B2*k2 + B3*k3 + B4*k4 + B5*k5 + B6*k6, y);
            float k7 = mlp(ynew);
            float yerr = dtc * (E1*k1 + E2*k2 + E3*k3 + E4*k4 + E5*k5 + E6*k6 + E7*k7);
            float sc = fmaf(0.01f, fmaxf(fabsf(y), fabsf(ynew)), 1e-4f);
            float e = yerr / sc;          // keep IEEE: feeds the accept branch
            float e2 = e * e;
            e2 += __shfl_xor(e2, 1); e2 += __shfl_xor(e2, 2);
            e2 += __shfl_xor(e2, 4); e2 += __shfl_xor(e2, 8);
            float err = sqrtf(e2 * 0.0625f);
            if (err <= 1.0f) { y = ynew; t += dtc; k1 = k7; }  // FSAL
            float fac = 0.9f * exp2f(-0.2f * log2f(fmaxf(err, 1e-10f)));
            fac = fminf(fmaxf(fac, 0.2f), 10.0f);
            dt = dtc * fac;
        }
        // ---------------- GRU observation update ----------------
        float x0 = s_x[2*l], x1 = s_x[2*l + 1];
        // hg = Whh[jg,:] . y via readlane (canonical order)
        float h0 = 0.f, h1 = 0.f, h2 = 0.f, h3 = 0.f;
        #pragma unroll
        for (int k = 0; k < 16; k += 4) {
            h0 = fmaf(whs[k + 0], RL(y, k + 0), h0);
            h1 = fmaf(whs[k + 1], RL(y, k + 1), h1);
            h2 = fmaf(whs[k + 2], RL(y, k + 2), h2);
            h3 = fmaf(whs[k + 3], RL(y, k + 3), h3);
        }
        float hg = (h0 + h2) + (h1 + h3);
        float ig = fmaf(wih0, x0, fmaf(wih1, x1, bihj));
        if (j < 48) { s_ig[j] = ig; s_hg[j] = hg; }
        LDSFENCE();     // same-wave DS in-order; stop IR reorder
        float ir = s_ig[i16], iz = s_ig[16+i16], in_ = s_ig[32+i16];
        float hr = s_hg[i16], hz = s_hg[16+i16], hn = s_hg[32+i16];
        float r = sigm_f(ir + hr);
        float z = sigm_f(iz + hz);
        float n = tanh_f(fmaf(r, hn + bnr, in_));
        y = n + z * (y - n);
        LDSFENCE();     // protect s_ig/s_hg before next iteration's writes
    }

    // ---------------- projection: out[b] = Wp . h + bp ----------------
    float pv = y * wpr;
    pv += __shfl_xor(pv, 1); pv += __shfl_xor(pv, 2);
    pv += __shfl_xor(pv, 4); pv += __shfl_xor(pv, 8);
    if (j == 0) out[b] = pv + bp[0];
}

extern "C" void kernel_launch(void* const* d_in, const int* in_sizes, int n_in,
                              void* d_out, int out_size, void* d_ws, size_t ws_size,
                              hipStream_t stream)
{
    odern_kernel<<<dim3(512), dim3(64), 0, stream>>>(
        (const float*)d_in[0],
        (const float*)d_in[1],  (const float*)d_in[2],
        (const float*)d_in[3],  (const float*)d_in[4],
        (const float*)d_in[5],  (const float*)d_in[6],
        (const float*)d_in[7],  (const float*)d_in[8],
        (const float*)d_in[9],  (const float*)d_in[10],
        (const float*)d_in[11], (const float*)d_in[12],
        (const float*)d_in[13], (const float*)d_in[14],
        (float*)d_out);
}